// Round 6
// baseline (317.063 us; speedup 1.0000x reference)
//
#include <hip/hip_runtime.h>
#include <stdint.h>
#include <math.h>

typedef __bf16 bf16;
typedef __attribute__((ext_vector_type(8))) __bf16 bf16x8;
typedef __attribute__((ext_vector_type(4))) __bf16 bf16x4;
typedef __attribute__((ext_vector_type(4))) float f32x4;

#define MFMA_BF16(a, b, c) __builtin_amdgcn_mfma_f32_16x16x32_bf16((a), (b), (c), 0, 0, 0)

#if __has_builtin(__builtin_amdgcn_exp2f)
#define EXP2F __builtin_amdgcn_exp2f
#else
#define EXP2F exp2f
#endif

// scale = 1/sqrt(64) * log2(e): folded into Q so softmax = exp2(s)
#define QSCALE 0.18033688011112042f

// async global->LDS, 16B per lane. LDS dest must be linear in lane order.
__device__ __forceinline__ void gl_lds16(const bf16* g, bf16* l) {
  __builtin_amdgcn_global_load_lds(
      (__attribute__((address_space(1))) unsigned int*)(uintptr_t)(g),
      (__attribute__((address_space(3))) unsigned int*)(l),
      16, 0, 0);
}

// ---------------------------------------------------------------------------
// prep: blocks [0,6144): fp32->bf16 convert of q,k,v (8 elems/thread).
//       blocks [6144,7168): weight transpose+convert dst[n][k]=(bf16)src[k][n].
// ---------------------------------------------------------------------------
__global__ __launch_bounds__(256) void prep(
    const float* __restrict__ q, const float* __restrict__ k,
    const float* __restrict__ v, bf16* __restrict__ qb,
    bf16* __restrict__ kb, bf16* __restrict__ vb,
    const float* __restrict__ W0, const float* __restrict__ W1,
    const float* __restrict__ W2, const float* __restrict__ W3,
    bf16* __restrict__ Wt)
{
  __shared__ float tile[64][65];
  const int tid = threadIdx.x;
  const int bid = blockIdx.x;
  if (bid < 6144) {
    const int z = bid >> 11;            // 2048 blocks per tensor
    const int idx = bid & 2047;
    const float* s = (z == 0) ? q : (z == 1) ? k : v;
    bf16* d = (z == 0) ? qb : (z == 1) ? kb : vb;
    size_t i = ((size_t)idx * 256 + tid) * 8;
    float4 a = *(const float4*)(s + i);
    float4 b = *(const float4*)(s + i + 4);
    bf16x8 o;
    o[0] = (bf16)a.x; o[1] = (bf16)a.y; o[2] = (bf16)a.z; o[3] = (bf16)a.w;
    o[4] = (bf16)b.x; o[5] = (bf16)b.y; o[6] = (bf16)b.z; o[7] = (bf16)b.w;
    *(bf16x8*)(d + i) = o;
  } else {
    const int t = bid - 6144;
    const int z = t >> 8;
    const int rem = t & 255;
    const int r0 = (rem >> 4) * 64, c0 = (rem & 15) * 64;
    const float* src = (z == 0) ? W0 : (z == 1) ? W1 : (z == 2) ? W2 : W3;
    bf16* dst = Wt + (size_t)z * (1024 * 1024);
#pragma unroll
    for (int h = 0; h < 2; ++h) {
      int qq = tid + h * 256;
      int row = qq >> 3, cc = qq & 7;
      float4 a = *(const float4*)(src + (size_t)(r0 + row) * 1024 + c0 + cc * 8);
      float4 b = *(const float4*)(src + (size_t)(r0 + row) * 1024 + c0 + cc * 8 + 4);
      tile[row][cc * 8 + 0] = a.x; tile[row][cc * 8 + 1] = a.y;
      tile[row][cc * 8 + 2] = a.z; tile[row][cc * 8 + 3] = a.w;
      tile[row][cc * 8 + 4] = b.x; tile[row][cc * 8 + 5] = b.y;
      tile[row][cc * 8 + 6] = b.z; tile[row][cc * 8 + 7] = b.w;
    }
    __syncthreads();
#pragma unroll
    for (int h = 0; h < 2; ++h) {
      int qq = tid + h * 256;
      int row = qq >> 3, cc = qq & 7;
      bf16x8 o;
#pragma unroll
      for (int e = 0; e < 8; ++e) o[e] = (bf16)tile[cc * 8 + e][row];
      *(bf16x8*)(dst + (size_t)(c0 + row) * 1024 + r0 + cc * 8) = o;
    }
  }
}

// ---------------------------------------------------------------------------
// GEMM: C[4096,1024] = A[4096,1024](bf16) * W + bias(fp32), Wt = W^T [n][k] bf16.
// 128x128 tile, BK=32, 4 waves, 16x16x32 bf16 MFMA, global_load_lds staging,
// XOR-swizzled 16B chunks.
// MODE 0 (swapped, W as A-operand): out[b,h,s,d] bf16 * QSCALE  (Q)
// MODE 1 (swapped): out[b,h,s,d] bf16, + fp32 kpe[h][d][s]      (K_eff)
// MODE 2 (normal):  out[b,h,d,t] bf16 (V^T; consecutive regs = t)
// ---------------------------------------------------------------------------
template <int MODE>
__device__ __forceinline__ void gemm_body(
    const bf16* __restrict__ A, const bf16* __restrict__ Wt,
    const float* __restrict__ bias, const float* __restrict__ kpe,
    void* __restrict__ out_v)
{
  __shared__ __align__(16) bf16 As[128 * 32];
  __shared__ __align__(16) bf16 Bs[128 * 32];
  const int tid = threadIdx.x;
  const int w = tid >> 6, lane = tid & 63;
  const int lm = lane & 15, quad = lane >> 4;
  const int wm = w >> 1, wn = w & 1;
  const int m0 = blockIdx.y * 128, n0 = blockIdx.x * 128;

  f32x4 zero4 = {0.f, 0.f, 0.f, 0.f};
  f32x4 acc[4][4];
#pragma unroll
  for (int i = 0; i < 4; ++i)
#pragma unroll
    for (int j = 0; j < 4; ++j) acc[i][j] = zero4;

  for (int kb = 0; kb < 32; ++kb) {
    __syncthreads();
#pragma unroll
    for (int h = 0; h < 2; ++h) {
      int qq = tid + h * 256;
      int row = qq >> 2, cs = qq & 3;
      int cc = cs ^ ((row >> 1) & 3);
      gl_lds16(A + (size_t)(m0 + row) * 1024 + kb * 32 + cc * 8, As + qq * 8);
      gl_lds16(Wt + (size_t)(n0 + row) * 1024 + kb * 32 + cc * 8, Bs + qq * 8);
    }
    __syncthreads();

    bf16x8 af[4], wf[4];
#pragma unroll
    for (int j = 0; j < 4; ++j) {
      int row = wm * 64 + j * 16 + lm;
      af[j] = *(const bf16x8*)(As + row * 32 + ((quad ^ ((row >> 1) & 3)) * 8));
    }
#pragma unroll
    for (int i = 0; i < 4; ++i) {
      int row = wn * 64 + i * 16 + lm;
      wf[i] = *(const bf16x8*)(Bs + row * 32 + ((quad ^ ((row >> 1) & 3)) * 8));
    }
#pragma unroll
    for (int i = 0; i < 4; ++i)
#pragma unroll
      for (int j = 0; j < 4; ++j) {
        if (MODE == 2)
          acc[i][j] = MFMA_BF16(af[j], wf[i], acc[i][j]);   // rows = m (t)
        else
          acc[i][j] = MFMA_BF16(wf[i], af[j], acc[i][j]);   // rows = n (d)
      }
  }

  if (MODE == 2) {
    // rows = m=t: acc[i][j][r] = C[t = wm*64+j*16+quad*4+r][d = wn*64+i*16+lm]
#pragma unroll
    for (int i = 0; i < 4; ++i) {
      const int ng = n0 + wn * 64 + i * 16 + lm;
      const int hh = ng >> 6, d = ng & 63;
      const float bv = bias[ng];
#pragma unroll
      for (int j = 0; j < 4; ++j) {
        const int mg = m0 + wm * 64 + j * 16 + quad * 4;  // t base (4 consec)
        const int b = mg >> 11, s = mg & 2047;
        bf16x4 o;
#pragma unroll
        for (int r = 0; r < 4; ++r) o[r] = (bf16)(acc[i][j][r] + bv);
        *(bf16x4*)((bf16*)out_v +
                   (((size_t)(b * 16 + hh)) * 64 + d) * 2048 + s) = o;
      }
    }
  } else {
    // rows = n=d: acc[i][j][r] = C[m = wm*64+j*16+lm][n = wn*64+i*16+quad*4+r]
#pragma unroll
    for (int i = 0; i < 4; ++i) {
      const int nb = n0 + wn * 64 + i * 16 + quad * 4;  // d base (4 consec)
      const float4 bv4 = *(const float4*)(bias + nb);
      const int hh = nb >> 6, db = nb & 63;
#pragma unroll
      for (int j = 0; j < 4; ++j) {
        const int mg = m0 + wm * 64 + j * 16 + lm;
        const int b = mg >> 11, s = mg & 2047;
        bf16x4 o;
#pragma unroll
        for (int r = 0; r < 4; ++r) {
          float val = acc[i][j][r] + ((const float*)&bv4)[r];
          if (MODE == 0) val *= QSCALE;
          if (MODE == 1)
            val += kpe[((size_t)(hh * 64 + db + r)) * 2048 + s];
          o[r] = (bf16)val;
        }
        *(bf16x4*)((bf16*)out_v +
                   (((size_t)(b * 16 + hh)) * 2048 + s) * 64 + db) = o;
      }
    }
  }
}

__global__ __launch_bounds__(256) void qkv_gemm(
    const bf16* __restrict__ qb, const bf16* __restrict__ kb, const bf16* __restrict__ vb,
    const bf16* __restrict__ Wt, const float* __restrict__ biq,
    const float* __restrict__ bik, const float* __restrict__ biv,
    const float* __restrict__ kpe,
    bf16* __restrict__ Qs, bf16* __restrict__ Ks, bf16* __restrict__ Vts)
{
  const int z = blockIdx.z;
  if (z == 0) {
    gemm_body<0>(qb, Wt, biq, nullptr, Qs);
  } else if (z == 1) {
    gemm_body<1>(kb, Wt + (size_t)1 * 1024 * 1024, bik, kpe, Ks);
  } else {
    gemm_body<2>(vb, Wt + (size_t)2 * 1024 * 1024, biv, nullptr, Vts);
  }
}

// ---------------------------------------------------------------------------
// Output GEMM, 128x64 tiles -> 512 blocks (2/CU; the 128x128 version ran at
// 1 block/CU and sat in barrier drain). Swapped orientation, fp32 out.
// Waves: w = m-subtile (32 rows each); each wave does full n=64.
// ---------------------------------------------------------------------------
__global__ __launch_bounds__(256) void out_gemm(
    const bf16* __restrict__ A, const bf16* __restrict__ Wt,
    const float* __restrict__ bias, float* __restrict__ out)
{
  __shared__ __align__(16) bf16 As[128 * 32];
  __shared__ __align__(16) bf16 Bs[64 * 32];
  const int tid = threadIdx.x;
  const int w = tid >> 6, lane = tid & 63;
  const int lm = lane & 15, quad = lane >> 4;
  const int m0 = blockIdx.y * 128, n0 = blockIdx.x * 64;

  f32x4 zero4 = {0.f, 0.f, 0.f, 0.f};
  f32x4 acc[4][2];
#pragma unroll
  for (int i = 0; i < 4; ++i)
#pragma unroll
    for (int j = 0; j < 2; ++j) acc[i][j] = zero4;

  for (int kb = 0; kb < 32; ++kb) {
    __syncthreads();
#pragma unroll
    for (int h = 0; h < 2; ++h) {
      int qq = tid + h * 256;
      int row = qq >> 2, cs = qq & 3;
      int cc = cs ^ ((row >> 1) & 3);
      gl_lds16(A + (size_t)(m0 + row) * 1024 + kb * 32 + cc * 8, As + qq * 8);
    }
    {
      int row = tid >> 2, cs = tid & 3;
      int cc = cs ^ ((row >> 1) & 3);
      gl_lds16(Wt + (size_t)(n0 + row) * 1024 + kb * 32 + cc * 8, Bs + tid * 8);
    }
    __syncthreads();

    bf16x8 af[2], wf[4];
#pragma unroll
    for (int j = 0; j < 2; ++j) {
      int row = w * 32 + j * 16 + lm;
      af[j] = *(const bf16x8*)(As + row * 32 + ((quad ^ ((row >> 1) & 3)) * 8));
    }
#pragma unroll
    for (int i = 0; i < 4; ++i) {
      int row = i * 16 + lm;
      wf[i] = *(const bf16x8*)(Bs + row * 32 + ((quad ^ ((row >> 1) & 3)) * 8));
    }
#pragma unroll
    for (int i = 0; i < 4; ++i)
#pragma unroll
      for (int j = 0; j < 2; ++j)
        acc[i][j] = MFMA_BF16(wf[i], af[j], acc[i][j]);  // rows = n
  }

  // rows = n: acc[i][j][r] = C[m = w*32+j*16+lm][n = i*16+quad*4+r]
#pragma unroll
  for (int i = 0; i < 4; ++i) {
    const int nb = n0 + i * 16 + quad * 4;
    const float4 bv4 = *(const float4*)(bias + nb);
#pragma unroll
    for (int j = 0; j < 2; ++j) {
      const int mg = m0 + w * 32 + j * 16 + lm;
      float4 o;
      o.x = acc[i][j][0] + bv4.x; o.y = acc[i][j][1] + bv4.y;
      o.z = acc[i][j][2] + bv4.z; o.w = acc[i][j][3] + bv4.w;
      *(float4*)(out + (size_t)mg * 1024 + nb) = o;
    }
  }
}

// ---------------------------------------------------------------------------
// Flash attention, BARRIER-FREE K-loop. No-max softmax (additive l/O), Q
// pre-scaled. Br=128, 4 waves x 32 queries. K/V/Q fragments load DIRECTLY
// global->VGPR: per instruction a wave covers 16 rows x 64B full sectors
// (fully coalesced); L1/L2 serve cross-wave/block re-reads. LDS = Ps only
// (wave-private rows; in-wave lgkmcnt orders write->read, no barrier).
// ---------------------------------------------------------------------------
#define PST 76  // Ps row stride (elems); measured 0 bank conflicts

__global__ __launch_bounds__(256) void flash_attn(
    const bf16* __restrict__ Q, const bf16* __restrict__ K,
    const bf16* __restrict__ Vt, bf16* __restrict__ O)
{
  __shared__ __align__(16) bf16 Ps[128 * PST];

  const int tid = threadIdx.x;
  const int w = tid >> 6, lane = tid & 63;
  const int lm = lane & 15, quad = lane >> 4;
  const int bh = blockIdx.y;
  const int s0 = blockIdx.x * 128;
  const size_t qkbase = (size_t)bh * (2048 * 64);
  const size_t vbase = (size_t)bh * (64 * 2048);

  // Q fragments direct from global: B-operand rows s, k-chunks quad / quad+4
  bf16x8 qa[2][2];
#pragma unroll
  for (int g = 0; g < 2; ++g) {
    const bf16* qp = Q + qkbase + (size_t)(s0 + w * 32 + g * 16 + lm) * 64;
    qa[g][0] = *(const bf16x8*)(qp + quad * 8);
    qa[g][1] = *(const bf16x8*)(qp + 32 + quad * 8);
  }

  f32x4 zero4 = {0.f, 0.f, 0.f, 0.f};
  float l_part[2] = {0.f, 0.f};
  f32x4 oacc[2][4];
#pragma unroll
  for (int g = 0; g < 2; ++g)
#pragma unroll
    for (int dt = 0; dt < 4; ++dt) oacc[g][dt] = zero4;

  const int prow[2] = {(w * 32 + lm) * PST, (w * 32 + 16 + lm) * PST};

  // invariant row bases (compiler hoists; inner loop is +t0 induction)
  const bf16* kp = K + qkbase + (size_t)lm * 64 + quad * 8;
  const bf16* vp = Vt + vbase + (size_t)lm * 2048 + quad * 8;

#pragma unroll 2
  for (int kt = 0; kt < 32; ++kt) {
    const int t0 = kt * 64;

    // K tile fragments: rows t = c*16+lm (A-operand)
    bf16x8 kf[4][2];
#pragma unroll
    for (int c = 0; c < 4; ++c) {
      const bf16* p = kp + (size_t)(t0 + c * 16) * 64;
      kf[c][0] = *(const bf16x8*)(p);
      kf[c][1] = *(const bf16x8*)(p + 32);
    }
    // V^T tile fragments: rows d = dt*16+lm (A-operand), k-dim = t
    bf16x8 vf[4][2];
#pragma unroll
    for (int dt = 0; dt < 4; ++dt) {
      const bf16* p = vp + (size_t)(dt * 16) * 2048 + t0;
      vf[dt][0] = *(const bf16x8*)(p);
      vf[dt][1] = *(const bf16x8*)(p + 32);
    }

    // St = K·Q^T per group; p = exp2(st); pack P rows (wave-private)
#pragma unroll
    for (int c = 0; c < 4; ++c) {
#pragma unroll
      for (int g = 0; g < 2; ++g) {
        f32x4 z = MFMA_BF16(kf[c][0], qa[g][0], zero4);
        f32x4 st = MFMA_BF16(kf[c][1], qa[g][1], z);
        bf16x4 pk;
#pragma unroll
        for (int r = 0; r < 4; ++r) {
          float p = EXP2F(st[r]);
          l_part[g] += p;
          pk[r] = (bf16)p;
        }
        *(bf16x4*)(Ps + prow[g] + c * 16 + quad * 4) = pk;
      }
    }

    // O^T += V^T · P^T
    bf16x8 pa[2][2];
#pragma unroll
    for (int g = 0; g < 2; ++g) {
      pa[g][0] = *(const bf16x8*)(Ps + prow[g] + quad * 8);
      pa[g][1] = *(const bf16x8*)(Ps + prow[g] + 32 + quad * 8);
    }
#pragma unroll
    for (int dt = 0; dt < 4; ++dt)
#pragma unroll
      for (int g = 0; g < 2; ++g) {
        oacc[g][dt] = MFMA_BF16(vf[dt][0], pa[g][0], oacc[g][dt]);
        oacc[g][dt] = MFMA_BF16(vf[dt][1], pa[g][1], oacc[g][dt]);
      }
  }

  // final denom (2 shuffles/group), normalize, bounce O^T rows through Ps
  const int b = bh >> 4, hh = bh & 15;
#pragma unroll
  for (int g = 0; g < 2; ++g) {
    float l = l_part[g];
    l += __shfl_xor(l, 16, 64);
    l += __shfl_xor(l, 32, 64);
    float inv = 1.f / l;
#pragma unroll
    for (int dt = 0; dt < 4; ++dt)
#pragma unroll
      for (int r = 0; r < 4; ++r)
        Ps[prow[g] + dt * 16 + quad * 4 + r] = (bf16)(oacc[g][dt][r] * inv);

    const int srow = s0 + w * 32 + g * 16 + lm;
    const size_t ob = ((size_t)(b * 2048 + srow)) * 1024 + hh * 64;
#pragma unroll
    for (int half = 0; half < 2; ++half) {
      bf16x8 ov = *(const bf16x8*)(Ps + prow[g] + (half * 4 + quad) * 8);
      *(bf16x8*)(O + ob + (half * 4 + quad) * 8) = ov;
    }
  }
}

// ---------------------------------------------------------------------------
extern "C" void kernel_launch(void* const* d_in, const int* in_sizes, int n_in,
                              void* d_out, int out_size, void* d_ws, size_t ws_size,
                              hipStream_t stream) {
  (void)in_sizes; (void)n_in; (void)out_size; (void)ws_size;
  const float* q   = (const float*)d_in[0];
  const float* k   = (const float*)d_in[1];
  const float* v   = (const float*)d_in[2];
  const float* kpe = (const float*)d_in[3];
  const float* Wq  = (const float*)d_in[4];
  const float* bq  = (const float*)d_in[5];
  const float* Wk  = (const float*)d_in[6];
  const float* bk  = (const float*)d_in[7];
  const float* Wv  = (const float*)d_in[8];
  const float* bv  = (const float*)d_in[9];
  const float* Wo  = (const float*)d_in[10];
  const float* bo  = (const float*)d_in[11];

  const size_t NT = 4u * 1024 * 1024;  // 4M elems per [4096,1024] tensor
  bf16* ws  = (bf16*)d_ws;
  bf16* Wt  = ws;            // 4 x 1M elems (bf16 W^T for Wq,Wk,Wv,Wo)
  bf16* qb  = Wt + NT;       // bf16 copies of q,k,v
  bf16* kb  = qb + NT;
  bf16* vb  = kb + NT;
  bf16* Qs  = vb + NT;       // [bh][s][d], pre-scaled
  bf16* Ks  = Qs + NT;       // K_eff [bh][t][d] (kpe folded in epilogue)
  bf16* Vts = Ks + NT;       // V^T  [bh][d][t] (direct from GEMM)
  bf16* Oa  = Vts + NT;      // attn out [b][s][h*64+d]

  prep<<<dim3(7168), 256, 0, stream>>>(q, k, v, qb, kb, vb, Wq, Wk, Wv, Wo, Wt);
  qkv_gemm<<<dim3(8, 32, 3), 256, 0, stream>>>(qb, kb, vb, Wt, bq, bk, bv, kpe,
                                               Qs, Ks, Vts);
  flash_attn<<<dim3(16, 32), 256, 0, stream>>>(Qs, Ks, Vts, Oa);
  out_gemm<<<dim3(16, 32), 256, 0, stream>>>(Oa, Wt + 3u * 1024 * 1024, bo,
                                             (float*)d_out);
}

// Round 7
// 264.517 us; speedup vs baseline: 1.1986x; 1.1986x over previous
//
#include <hip/hip_runtime.h>
#include <stdint.h>
#include <math.h>

typedef __bf16 bf16;
typedef __attribute__((ext_vector_type(8))) __bf16 bf16x8;
typedef __attribute__((ext_vector_type(4))) __bf16 bf16x4;
typedef __attribute__((ext_vector_type(4))) float f32x4;

#define MFMA_BF16(a, b, c) __builtin_amdgcn_mfma_f32_16x16x32_bf16((a), (b), (c), 0, 0, 0)

#if __has_builtin(__builtin_amdgcn_exp2f)
#define EXP2F __builtin_amdgcn_exp2f
#else
#define EXP2F exp2f
#endif

// scale = 1/sqrt(64) * log2(e): folded into Q so softmax = exp2(s)
#define QSCALE 0.18033688011112042f

// async global->LDS, 16B per lane. LDS dest must be linear in lane order.
__device__ __forceinline__ void gl_lds16(const bf16* g, bf16* l) {
  __builtin_amdgcn_global_load_lds(
      (__attribute__((address_space(1))) unsigned int*)(uintptr_t)(g),
      (__attribute__((address_space(3))) unsigned int*)(l),
      16, 0, 0);
}

// ---------------------------------------------------------------------------
// prep: blocks [0,6144): fp32->bf16 convert of q,k,v (8 elems/thread).
//       blocks [6144,7168): weight transpose+convert dst[n][k]=(bf16)src[k][n].
// ---------------------------------------------------------------------------
__global__ __launch_bounds__(256) void prep(
    const float* __restrict__ q, const float* __restrict__ k,
    const float* __restrict__ v, bf16* __restrict__ qb,
    bf16* __restrict__ kb, bf16* __restrict__ vb,
    const float* __restrict__ W0, const float* __restrict__ W1,
    const float* __restrict__ W2, const float* __restrict__ W3,
    bf16* __restrict__ Wt)
{
  __shared__ float tile[64][65];
  const int tid = threadIdx.x;
  const int bid = blockIdx.x;
  if (bid < 6144) {
    const int z = bid >> 11;            // 2048 blocks per tensor
    const int idx = bid & 2047;
    const float* s = (z == 0) ? q : (z == 1) ? k : v;
    bf16* d = (z == 0) ? qb : (z == 1) ? kb : vb;
    size_t i = ((size_t)idx * 256 + tid) * 8;
    float4 a = *(const float4*)(s + i);
    float4 b = *(const float4*)(s + i + 4);
    bf16x8 o;
    o[0] = (bf16)a.x; o[1] = (bf16)a.y; o[2] = (bf16)a.z; o[3] = (bf16)a.w;
    o[4] = (bf16)b.x; o[5] = (bf16)b.y; o[6] = (bf16)b.z; o[7] = (bf16)b.w;
    *(bf16x8*)(d + i) = o;
  } else {
    const int t = bid - 6144;
    const int z = t >> 8;
    const int rem = t & 255;
    const int r0 = (rem >> 4) * 64, c0 = (rem & 15) * 64;
    const float* src = (z == 0) ? W0 : (z == 1) ? W1 : (z == 2) ? W2 : W3;
    bf16* dst = Wt + (size_t)z * (1024 * 1024);
#pragma unroll
    for (int h = 0; h < 2; ++h) {
      int qq = tid + h * 256;
      int row = qq >> 3, cc = qq & 7;
      float4 a = *(const float4*)(src + (size_t)(r0 + row) * 1024 + c0 + cc * 8);
      float4 b = *(const float4*)(src + (size_t)(r0 + row) * 1024 + c0 + cc * 8 + 4);
      tile[row][cc * 8 + 0] = a.x; tile[row][cc * 8 + 1] = a.y;
      tile[row][cc * 8 + 2] = a.z; tile[row][cc * 8 + 3] = a.w;
      tile[row][cc * 8 + 4] = b.x; tile[row][cc * 8 + 5] = b.y;
      tile[row][cc * 8 + 6] = b.z; tile[row][cc * 8 + 7] = b.w;
    }
    __syncthreads();
#pragma unroll
    for (int h = 0; h < 2; ++h) {
      int qq = tid + h * 256;
      int row = qq >> 3, cc = qq & 7;
      bf16x8 o;
#pragma unroll
      for (int e = 0; e < 8; ++e) o[e] = (bf16)tile[cc * 8 + e][row];
      *(bf16x8*)(dst + (size_t)(c0 + row) * 1024 + r0 + cc * 8) = o;
    }
  }
}

// ---------------------------------------------------------------------------
// GEMM: C[4096,1024] = A[4096,1024](bf16) * W + bias(fp32), Wt = W^T [n][k] bf16.
// 128x128 tile, BK=32, 4 waves, 16x16x32 bf16 MFMA, global_load_lds staging,
// XOR-swizzled 16B chunks.
// MODE 0 (swapped, W as A-operand): out[b,h,s,d] bf16 * QSCALE  (Q)
// MODE 1 (swapped): out[b,h,s,d] bf16, + fp32 kpe[h][d][s]      (K_eff)
// MODE 2 (normal):  out[b,h,d,t] bf16 (V^T; consecutive regs = t)
// MODE 3 (swapped): fp32 row-major [m][n], float4 stores        (final)
// ---------------------------------------------------------------------------
template <int MODE>
__device__ __forceinline__ void gemm_body(
    const bf16* __restrict__ A, const bf16* __restrict__ Wt,
    const float* __restrict__ bias, const float* __restrict__ kpe,
    void* __restrict__ out_v)
{
  __shared__ __align__(16) bf16 As[128 * 32];
  __shared__ __align__(16) bf16 Bs[128 * 32];
  const int tid = threadIdx.x;
  const int w = tid >> 6, lane = tid & 63;
  const int lm = lane & 15, quad = lane >> 4;
  const int wm = w >> 1, wn = w & 1;
  const int m0 = blockIdx.y * 128, n0 = blockIdx.x * 128;

  f32x4 zero4 = {0.f, 0.f, 0.f, 0.f};
  f32x4 acc[4][4];
#pragma unroll
  for (int i = 0; i < 4; ++i)
#pragma unroll
    for (int j = 0; j < 4; ++j) acc[i][j] = zero4;

  for (int kb = 0; kb < 32; ++kb) {
    __syncthreads();
#pragma unroll
    for (int h = 0; h < 2; ++h) {
      int qq = tid + h * 256;
      int row = qq >> 2, cs = qq & 3;
      int cc = cs ^ ((row >> 1) & 3);
      gl_lds16(A + (size_t)(m0 + row) * 1024 + kb * 32 + cc * 8, As + qq * 8);
      gl_lds16(Wt + (size_t)(n0 + row) * 1024 + kb * 32 + cc * 8, Bs + qq * 8);
    }
    __syncthreads();

    bf16x8 af[4], wf[4];
#pragma unroll
    for (int j = 0; j < 4; ++j) {
      int row = wm * 64 + j * 16 + lm;
      af[j] = *(const bf16x8*)(As + row * 32 + ((quad ^ ((row >> 1) & 3)) * 8));
    }
#pragma unroll
    for (int i = 0; i < 4; ++i) {
      int row = wn * 64 + i * 16 + lm;
      wf[i] = *(const bf16x8*)(Bs + row * 32 + ((quad ^ ((row >> 1) & 3)) * 8));
    }
#pragma unroll
    for (int i = 0; i < 4; ++i)
#pragma unroll
      for (int j = 0; j < 4; ++j) {
        if (MODE == 2)
          acc[i][j] = MFMA_BF16(af[j], wf[i], acc[i][j]);   // rows = m (t)
        else
          acc[i][j] = MFMA_BF16(wf[i], af[j], acc[i][j]);   // rows = n (d)
      }
  }

  if (MODE == 2) {
    // rows = m=t: acc[i][j][r] = C[t = wm*64+j*16+quad*4+r][d = wn*64+i*16+lm]
#pragma unroll
    for (int i = 0; i < 4; ++i) {
      const int ng = n0 + wn * 64 + i * 16 + lm;
      const int hh = ng >> 6, d = ng & 63;
      const float bv = bias[ng];
#pragma unroll
      for (int j = 0; j < 4; ++j) {
        const int mg = m0 + wm * 64 + j * 16 + quad * 4;  // t base (4 consec)
        const int b = mg >> 11, s = mg & 2047;
        bf16x4 o;
#pragma unroll
        for (int r = 0; r < 4; ++r) o[r] = (bf16)(acc[i][j][r] + bv);
        *(bf16x4*)((bf16*)out_v +
                   (((size_t)(b * 16 + hh)) * 64 + d) * 2048 + s) = o;
      }
    }
  } else {
    // rows = n=d: acc[i][j][r] = C[m = wm*64+j*16+lm][n = wn*64+i*16+quad*4+r]
#pragma unroll
    for (int i = 0; i < 4; ++i) {
      const int nb = n0 + wn * 64 + i * 16 + quad * 4;  // d base (4 consec)
      const float4 bv4 = *(const float4*)(bias + nb);
      const int hh = nb >> 6, db = nb & 63;
#pragma unroll
      for (int j = 0; j < 4; ++j) {
        const int mg = m0 + wm * 64 + j * 16 + lm;
        const int b = mg >> 11, s = mg & 2047;
        if (MODE == 3) {
          float4 o;
          o.x = acc[i][j][0] + bv4.x; o.y = acc[i][j][1] + bv4.y;
          o.z = acc[i][j][2] + bv4.z; o.w = acc[i][j][3] + bv4.w;
          *(float4*)((float*)out_v + (size_t)mg * 1024 + nb) = o;
        } else {
          bf16x4 o;
#pragma unroll
          for (int r = 0; r < 4; ++r) {
            float val = acc[i][j][r] + ((const float*)&bv4)[r];
            if (MODE == 0) val *= QSCALE;
            if (MODE == 1)
              val += kpe[((size_t)(hh * 64 + db + r)) * 2048 + s];
            o[r] = (bf16)val;
          }
          *(bf16x4*)((bf16*)out_v +
                     (((size_t)(b * 16 + hh)) * 2048 + s) * 64 + db) = o;
        }
      }
    }
  }
}

__global__ __launch_bounds__(256) void qkv_gemm(
    const bf16* __restrict__ qb, const bf16* __restrict__ kb, const bf16* __restrict__ vb,
    const bf16* __restrict__ Wt, const float* __restrict__ biq,
    const float* __restrict__ bik, const float* __restrict__ biv,
    const float* __restrict__ kpe,
    bf16* __restrict__ Qs, bf16* __restrict__ Ks, bf16* __restrict__ Vts)
{
  const int z = blockIdx.z;
  if (z == 0) {
    gemm_body<0>(qb, Wt, biq, nullptr, Qs);
  } else if (z == 1) {
    gemm_body<1>(kb, Wt + (size_t)1 * 1024 * 1024, bik, kpe, Ks);
  } else {
    gemm_body<2>(vb, Wt + (size_t)2 * 1024 * 1024, biv, nullptr, Vts);
  }
}

__global__ __launch_bounds__(256) void out_gemm(
    const bf16* __restrict__ A, const bf16* __restrict__ Wt,
    const float* __restrict__ bias, float* __restrict__ out)
{
  gemm_body<3>(A, Wt, bias, nullptr, out);
}

// ---------------------------------------------------------------------------
// Flash attention with INTRA-BLOCK t-SPLIT. No-max softmax => l and O are
// purely additive over t, so wave-group 0 (waves 0-3) handles t in [0,1024)
// and group 1 (waves 4-7) t in [1024,2048), each staging its own K/V tiles
// via global_load_lds (R6 showed direct global->VGPR fragments stall on
// vmcnt). 32 queries/wave (R5's LDS-traffic-optimal shape) at 16 waves/CU
// (R4's occupancy): LDS-pipe floor ~32us. Partials combine through LDS.
// ---------------------------------------------------------------------------
#define PST 76  // Ps row stride (elems); R5-measured 0 bank conflicts

__global__ __launch_bounds__(512) void flash_attn(
    const bf16* __restrict__ Q, const bf16* __restrict__ K,
    const bf16* __restrict__ Vt, bf16* __restrict__ O)
{
  __shared__ __align__(16) bf16 Kt[2][64 * 64];
  __shared__ __align__(16) bf16 Vs[2][64 * 64];
  __shared__ __align__(16) bf16 Ps[2 * 128 * PST];  // per-group P; fp32 Xs later
  __shared__ float Ls[128];

  const int tid = threadIdx.x;
  const int w = tid >> 6, lane = tid & 63;
  const int grp = w >> 2, wl = w & 3;
  const int lm = lane & 15, quad = lane >> 4;
  const int bh = blockIdx.y;
  const int s0 = blockIdx.x * 128;
  const size_t qkbase = (size_t)bh * (2048 * 64);
  const size_t vbase = (size_t)bh * (64 * 2048);
  const int tbase = grp * 1024;

  // Q fragments direct from global (one-time load; coalesced 16 rows x 64B)
  bf16x8 qa[2][2];
#pragma unroll
  for (int g = 0; g < 2; ++g) {
    const bf16* qp = Q + qkbase + (size_t)(s0 + wl * 32 + g * 16 + lm) * 64;
    qa[g][0] = *(const bf16x8*)(qp + quad * 8);
    qa[g][1] = *(const bf16x8*)(qp + 32 + quad * 8);
  }

  f32x4 zero4 = {0.f, 0.f, 0.f, 0.f};
  float l_part[2] = {0.f, 0.f};
  f32x4 oacc[2][4];
#pragma unroll
  for (int g = 0; g < 2; ++g)
#pragma unroll
    for (int dt = 0; dt < 4; ++dt) oacc[g][dt] = zero4;

  bf16* myPs = Ps + grp * (128 * PST);
  const int prow[2] = {(wl * 32 + lm) * PST, (wl * 32 + 16 + lm) * PST};
  const int gt = tid & 255;  // thread id within group (4 waves = 256)

  for (int kt = 0; kt < 16; ++kt) {
    const int t0 = tbase + kt * 64;
    __syncthreads();  // both groups done reading previous tiles
#pragma unroll
    for (int h = 0; h < 2; ++h) {
      int qq = gt + h * 256;
      int row = qq >> 3, cs = qq & 7;
      int cc = cs ^ (row & 7);
      gl_lds16(K + qkbase + (size_t)(t0 + row) * 64 + cc * 8, Kt[grp] + qq * 8);
      gl_lds16(Vt + vbase + (size_t)row * 2048 + t0 + cc * 8, Vs[grp] + qq * 8);
    }
    __syncthreads();  // loads landed

    // St = K.Q^T per group; p = exp2(st); pack P rows (wave-private)
#pragma unroll
    for (int c = 0; c < 4; ++c) {
      int row = c * 16 + lm;
      bf16x8 kb0 = *(const bf16x8*)(Kt[grp] + row * 64 + ((quad ^ (row & 7)) * 8));
      bf16x8 kb1 = *(const bf16x8*)(Kt[grp] + row * 64 + (((quad + 4) ^ (row & 7)) * 8));
#pragma unroll
      for (int g = 0; g < 2; ++g) {
        f32x4 z = MFMA_BF16(kb0, qa[g][0], zero4);
        f32x4 st = MFMA_BF16(kb1, qa[g][1], z);
        bf16x4 pk;
#pragma unroll
        for (int r = 0; r < 4; ++r) {
          float p = EXP2F(st[r]);
          l_part[g] += p;
          pk[r] = (bf16)p;
        }
        *(bf16x4*)(myPs + prow[g] + c * 16 + quad * 4) = pk;
      }
    }

    // O^T += V^T . P^T (in-wave lgkm ordering covers Ps write->read)
    bf16x8 pa[2][2];
#pragma unroll
    for (int g = 0; g < 2; ++g) {
      pa[g][0] = *(const bf16x8*)(myPs + prow[g] + quad * 8);
      pa[g][1] = *(const bf16x8*)(myPs + prow[g] + 32 + quad * 8);
    }
#pragma unroll
    for (int dt = 0; dt < 4; ++dt) {
      int row = dt * 16 + lm;
      bf16x8 va0 = *(const bf16x8*)(Vs[grp] + row * 64 + ((quad ^ (row & 7)) * 8));
      bf16x8 va1 = *(const bf16x8*)(Vs[grp] + row * 64 + (((quad + 4) ^ (row & 7)) * 8));
#pragma unroll
      for (int g = 0; g < 2; ++g) {
        oacc[g][dt] = MFMA_BF16(va0, pa[g][0], oacc[g][dt]);
        oacc[g][dt] = MFMA_BF16(va1, pa[g][1], oacc[g][dt]);
      }
    }
  }

  // combine: group 1 exports unnormalized O^T (fp32) + l through LDS;
  // group 0 adds, normalizes, stores. Xs stride 68 floats (2-way max).
  __syncthreads();  // all compute (incl. Ps reads) done before overlay
  float* Xs = (float*)Ps;  // 128 x 68 fp32 = 34.8KB <= 38.9KB
  if (grp == 1) {
#pragma unroll
    for (int g = 0; g < 2; ++g) {
      float l = l_part[g];
      l += __shfl_xor(l, 16, 64);
      l += __shfl_xor(l, 32, 64);
      const int s = wl * 32 + g * 16 + lm;
      if (quad == 0) Ls[s] = l;
#pragma unroll
      for (int dt = 0; dt < 4; ++dt)
        *(f32x4*)(Xs + s * 68 + dt * 16 + quad * 4) = oacc[g][dt];
    }
  }
  __syncthreads();
  if (grp == 0) {
    const int b = bh >> 4, hh = bh & 15;
#pragma unroll
    for (int g = 0; g < 2; ++g) {
      float l = l_part[g];
      l += __shfl_xor(l, 16, 64);
      l += __shfl_xor(l, 32, 64);
      const int s = wl * 32 + g * 16 + lm;
      l += Ls[s];
      const float inv = 1.f / l;
      const size_t ob = ((size_t)(b * 2048 + s0 + s)) * 1024 + hh * 64;
#pragma unroll
      for (int dt = 0; dt < 4; ++dt) {
        f32x4 x = *(const f32x4*)(Xs + s * 68 + dt * 16 + quad * 4);
        bf16x4 o;
#pragma unroll
        for (int r = 0; r < 4; ++r)
          o[r] = (bf16)((oacc[g][dt][r] + x[r]) * inv);
        *(bf16x4*)(O + ob + dt * 16 + quad * 4) = o;
      }
    }
  }
}

// ---------------------------------------------------------------------------
extern "C" void kernel_launch(void* const* d_in, const int* in_sizes, int n_in,
                              void* d_out, int out_size, void* d_ws, size_t ws_size,
                              hipStream_t stream) {
  (void)in_sizes; (void)n_in; (void)out_size; (void)ws_size;
  const float* q   = (const float*)d_in[0];
  const float* k   = (const float*)d_in[1];
  const float* v   = (const float*)d_in[2];
  const float* kpe = (const float*)d_in[3];
  const float* Wq  = (const float*)d_in[4];
  const float* bq  = (const float*)d_in[5];
  const float* Wk  = (const float*)d_in[6];
  const float* bk  = (const float*)d_in[7];
  const float* Wv  = (const float*)d_in[8];
  const float* bv  = (const float*)d_in[9];
  const float* Wo  = (const float*)d_in[10];
  const float* bo  = (const float*)d_in[11];

  const size_t NT = 4u * 1024 * 1024;  // 4M elems per [4096,1024] tensor
  bf16* ws  = (bf16*)d_ws;
  bf16* Wt  = ws;            // 4 x 1M elems (bf16 W^T for Wq,Wk,Wv,Wo)
  bf16* qb  = Wt + NT;       // bf16 copies of q,k,v
  bf16* kb  = qb + NT;
  bf16* vb  = kb + NT;
  bf16* Qs  = vb + NT;       // [bh][s][d], pre-scaled
  bf16* Ks  = Qs + NT;       // K_eff [bh][t][d] (kpe folded in epilogue)
  bf16* Vts = Ks + NT;       // V^T  [bh][d][t] (direct from GEMM)
  bf16* Oa  = Vts + NT;      // attn out [b][s][h*64+d]

  prep<<<dim3(7168), 256, 0, stream>>>(q, k, v, qb, kb, vb, Wq, Wk, Wv, Wo, Wt);
  qkv_gemm<<<dim3(8, 32, 3), 256, 0, stream>>>(qb, kb, vb, Wt, bq, bk, bv, kpe,
                                               Qs, Ks, Vts);
  flash_attn<<<dim3(16, 32), 512, 0, stream>>>(Qs, Ks, Vts, Oa);
  out_gemm<<<dim3(8, 32), 256, 0, stream>>>(Oa, Wt + 3u * 1024 * 1024, bo,
                                            (float*)d_out);
}

// Round 8
// 247.789 us; speedup vs baseline: 1.2796x; 1.0675x over previous
//
#include <hip/hip_runtime.h>
#include <stdint.h>
#include <math.h>

typedef __bf16 bf16;
typedef __attribute__((ext_vector_type(8))) __bf16 bf16x8;
typedef __attribute__((ext_vector_type(4))) __bf16 bf16x4;
typedef __attribute__((ext_vector_type(4))) float f32x4;

#define MFMA_BF16(a, b, c) __builtin_amdgcn_mfma_f32_16x16x32_bf16((a), (b), (c), 0, 0, 0)

#if __has_builtin(__builtin_amdgcn_exp2f)
#define EXP2F __builtin_amdgcn_exp2f
#else
#define EXP2F exp2f
#endif

// scale = 1/sqrt(64) * log2(e): folded into Q so softmax = exp2(s)
#define QSCALE 0.18033688011112042f

// async global->LDS, 16B per lane. LDS dest must be linear in lane order.
__device__ __forceinline__ void gl_lds16(const bf16* g, bf16* l) {
  __builtin_amdgcn_global_load_lds(
      (__attribute__((address_space(1))) unsigned int*)(uintptr_t)(g),
      (__attribute__((address_space(3))) unsigned int*)(l),
      16, 0, 0);
}

// ---------------------------------------------------------------------------
// prep: blocks [0,6144): fp32->bf16 convert of q,k,v (8 elems/thread).
//       blocks [6144,7168): weight transpose+convert dst[n][k]=(bf16)src[k][n].
// ---------------------------------------------------------------------------
__global__ __launch_bounds__(256) void prep(
    const float* __restrict__ q, const float* __restrict__ k,
    const float* __restrict__ v, bf16* __restrict__ qb,
    bf16* __restrict__ kb, bf16* __restrict__ vb,
    const float* __restrict__ W0, const float* __restrict__ W1,
    const float* __restrict__ W2, const float* __restrict__ W3,
    bf16* __restrict__ Wt)
{
  __shared__ float tile[64][65];
  const int tid = threadIdx.x;
  const int bid = blockIdx.x;
  if (bid < 6144) {
    const int z = bid >> 11;            // 2048 blocks per tensor
    const int idx = bid & 2047;
    const float* s = (z == 0) ? q : (z == 1) ? k : v;
    bf16* d = (z == 0) ? qb : (z == 1) ? kb : vb;
    size_t i = ((size_t)idx * 256 + tid) * 8;
    float4 a = *(const float4*)(s + i);
    float4 b = *(const float4*)(s + i + 4);
    bf16x8 o;
    o[0] = (bf16)a.x; o[1] = (bf16)a.y; o[2] = (bf16)a.z; o[3] = (bf16)a.w;
    o[4] = (bf16)b.x; o[5] = (bf16)b.y; o[6] = (bf16)b.z; o[7] = (bf16)b.w;
    *(bf16x8*)(d + i) = o;
  } else {
    const int t = bid - 6144;
    const int z = t >> 8;
    const int rem = t & 255;
    const int r0 = (rem >> 4) * 64, c0 = (rem & 15) * 64;
    const float* src = (z == 0) ? W0 : (z == 1) ? W1 : (z == 2) ? W2 : W3;
    bf16* dst = Wt + (size_t)z * (1024 * 1024);
#pragma unroll
    for (int h = 0; h < 2; ++h) {
      int qq = tid + h * 256;
      int row = qq >> 3, cc = qq & 7;
      float4 a = *(const float4*)(src + (size_t)(r0 + row) * 1024 + c0 + cc * 8);
      float4 b = *(const float4*)(src + (size_t)(r0 + row) * 1024 + c0 + cc * 8 + 4);
      tile[row][cc * 8 + 0] = a.x; tile[row][cc * 8 + 1] = a.y;
      tile[row][cc * 8 + 2] = a.z; tile[row][cc * 8 + 3] = a.w;
      tile[row][cc * 8 + 4] = b.x; tile[row][cc * 8 + 5] = b.y;
      tile[row][cc * 8 + 6] = b.z; tile[row][cc * 8 + 7] = b.w;
    }
    __syncthreads();
#pragma unroll
    for (int h = 0; h < 2; ++h) {
      int qq = tid + h * 256;
      int row = qq >> 3, cc = qq & 7;
      bf16x8 o;
#pragma unroll
      for (int e = 0; e < 8; ++e) o[e] = (bf16)tile[cc * 8 + e][row];
      *(bf16x8*)(dst + (size_t)(c0 + row) * 1024 + r0 + cc * 8) = o;
    }
  }
}

// ---------------------------------------------------------------------------
// GEMM: C[4096,1024] = A[4096,1024](bf16) * W + bias(fp32), Wt = W^T [n][k] bf16.
// 128x128 tile, BK=32, 4 waves, m97-style 2-barrier loop (3 blocks/CU).
// MODE 0 (swapped, W as A-operand): out[b,h,s,d] bf16 * QSCALE  (Q)
// MODE 1 (swapped): out[b,h,s,d] bf16, + fp32 kpe[h][d][s]      (K_eff)
// MODE 2 (normal):  out[b,h,d,t] bf16 (V^T; consecutive regs = t)
// ---------------------------------------------------------------------------
template <int MODE>
__device__ __forceinline__ void gemm_body(
    const bf16* __restrict__ A, const bf16* __restrict__ Wt,
    const float* __restrict__ bias, const float* __restrict__ kpe,
    void* __restrict__ out_v)
{
  __shared__ __align__(16) bf16 As[128 * 32];
  __shared__ __align__(16) bf16 Bs[128 * 32];
  const int tid = threadIdx.x;
  const int w = tid >> 6, lane = tid & 63;
  const int lm = lane & 15, quad = lane >> 4;
  const int wm = w >> 1, wn = w & 1;
  const int m0 = blockIdx.y * 128, n0 = blockIdx.x * 128;

  f32x4 zero4 = {0.f, 0.f, 0.f, 0.f};
  f32x4 acc[4][4];
#pragma unroll
  for (int i = 0; i < 4; ++i)
#pragma unroll
    for (int j = 0; j < 4; ++j) acc[i][j] = zero4;

  for (int kb = 0; kb < 32; ++kb) {
    __syncthreads();
#pragma unroll
    for (int h = 0; h < 2; ++h) {
      int qq = tid + h * 256;
      int row = qq >> 2, cs = qq & 3;
      int cc = cs ^ ((row >> 1) & 3);
      gl_lds16(A + (size_t)(m0 + row) * 1024 + kb * 32 + cc * 8, As + qq * 8);
      gl_lds16(Wt + (size_t)(n0 + row) * 1024 + kb * 32 + cc * 8, Bs + qq * 8);
    }
    __syncthreads();

    bf16x8 af[4], wf[4];
#pragma unroll
    for (int j = 0; j < 4; ++j) {
      int row = wm * 64 + j * 16 + lm;
      af[j] = *(const bf16x8*)(As + row * 32 + ((quad ^ ((row >> 1) & 3)) * 8));
    }
#pragma unroll
    for (int i = 0; i < 4; ++i) {
      int row = wn * 64 + i * 16 + lm;
      wf[i] = *(const bf16x8*)(Bs + row * 32 + ((quad ^ ((row >> 1) & 3)) * 8));
    }
#pragma unroll
    for (int i = 0; i < 4; ++i)
#pragma unroll
      for (int j = 0; j < 4; ++j) {
        if (MODE == 2)
          acc[i][j] = MFMA_BF16(af[j], wf[i], acc[i][j]);   // rows = m (t)
        else
          acc[i][j] = MFMA_BF16(wf[i], af[j], acc[i][j]);   // rows = n (d)
      }
  }

  if (MODE == 2) {
    // rows = m=t: acc[i][j][r] = C[t = wm*64+j*16+quad*4+r][d = wn*64+i*16+lm]
#pragma unroll
    for (int i = 0; i < 4; ++i) {
      const int ng = n0 + wn * 64 + i * 16 + lm;
      const int hh = ng >> 6, d = ng & 63;
      const float bv = bias[ng];
#pragma unroll
      for (int j = 0; j < 4; ++j) {
        const int mg = m0 + wm * 64 + j * 16 + quad * 4;  // t base (4 consec)
        const int b = mg >> 11, s = mg & 2047;
        bf16x4 o;
#pragma unroll
        for (int r = 0; r < 4; ++r) o[r] = (bf16)(acc[i][j][r] + bv);
        *(bf16x4*)((bf16*)out_v +
                   (((size_t)(b * 16 + hh)) * 64 + d) * 2048 + s) = o;
      }
    }
  } else {
    // rows = n=d: acc[i][j][r] = C[m = wm*64+j*16+lm][n = wn*64+i*16+quad*4+r]
#pragma unroll
    for (int i = 0; i < 4; ++i) {
      const int nb = n0 + wn * 64 + i * 16 + quad * 4;  // d base (4 consec)
      const float4 bv4 = *(const float4*)(bias + nb);
      const int hh = nb >> 6, db = nb & 63;
#pragma unroll
      for (int j = 0; j < 4; ++j) {
        const int mg = m0 + wm * 64 + j * 16 + lm;
        const int b = mg >> 11, s = mg & 2047;
        bf16x4 o;
#pragma unroll
        for (int r = 0; r < 4; ++r) {
          float val = acc[i][j][r] + ((const float*)&bv4)[r];
          if (MODE == 0) val *= QSCALE;
          if (MODE == 1)
            val += kpe[((size_t)(hh * 64 + db + r)) * 2048 + s];
          o[r] = (bf16)val;
        }
        *(bf16x4*)((bf16*)out_v +
                   (((size_t)(b * 16 + hh)) * 2048 + s) * 64 + db) = o;
      }
    }
  }
}

__global__ __launch_bounds__(256) void qkv_gemm(
    const bf16* __restrict__ qb, const bf16* __restrict__ kb, const bf16* __restrict__ vb,
    const bf16* __restrict__ Wt, const float* __restrict__ biq,
    const float* __restrict__ bik, const float* __restrict__ biv,
    const float* __restrict__ kpe,
    bf16* __restrict__ Qs, bf16* __restrict__ Ks, bf16* __restrict__ Vts)
{
  const int z = blockIdx.z;
  if (z == 0) {
    gemm_body<0>(qb, Wt, biq, nullptr, Qs);
  } else if (z == 1) {
    gemm_body<1>(kb, Wt + (size_t)1 * 1024 * 1024, bik, kpe, Ks);
  } else {
    gemm_body<2>(vb, Wt + (size_t)2 * 1024 * 1024, biv, nullptr, Vts);
  }
}

// ---------------------------------------------------------------------------
// Output GEMM, 128x64 tiles -> 512 blocks (2/CU vs 1/CU for 128x128).
// Swapped orientation (W as A-operand), fp32 out, float4 stores.
// ---------------------------------------------------------------------------
__global__ __launch_bounds__(256) void out_gemm(
    const bf16* __restrict__ A, const bf16* __restrict__ Wt,
    const float* __restrict__ bias, float* __restrict__ out)
{
  __shared__ __align__(16) bf16 As[128 * 32];
  __shared__ __align__(16) bf16 Bs[64 * 32];
  const int tid = threadIdx.x;
  const int w = tid >> 6, lane = tid & 63;
  const int lm = lane & 15, quad = lane >> 4;
  const int m0 = blockIdx.y * 128, n0 = blockIdx.x * 64;

  f32x4 zero4 = {0.f, 0.f, 0.f, 0.f};
  f32x4 acc[4][2];
#pragma unroll
  for (int i = 0; i < 4; ++i)
#pragma unroll
    for (int j = 0; j < 2; ++j) acc[i][j] = zero4;

  for (int kb = 0; kb < 32; ++kb) {
    __syncthreads();
#pragma unroll
    for (int h = 0; h < 2; ++h) {
      int qq = tid + h * 256;
      int row = qq >> 2, cs = qq & 3;
      int cc = cs ^ ((row >> 1) & 3);
      gl_lds16(A + (size_t)(m0 + row) * 1024 + kb * 32 + cc * 8, As + qq * 8);
    }
    {
      int row = tid >> 2, cs = tid & 3;
      int cc = cs ^ ((row >> 1) & 3);
      gl_lds16(Wt + (size_t)(n0 + row) * 1024 + kb * 32 + cc * 8, Bs + tid * 8);
    }
    __syncthreads();

    bf16x8 af[2], wf[4];
#pragma unroll
    for (int j = 0; j < 2; ++j) {
      int row = w * 32 + j * 16 + lm;
      af[j] = *(const bf16x8*)(As + row * 32 + ((quad ^ ((row >> 1) & 3)) * 8));
    }
#pragma unroll
    for (int i = 0; i < 4; ++i) {
      int row = i * 16 + lm;
      wf[i] = *(const bf16x8*)(Bs + row * 32 + ((quad ^ ((row >> 1) & 3)) * 8));
    }
#pragma unroll
    for (int i = 0; i < 4; ++i)
#pragma unroll
      for (int j = 0; j < 2; ++j)
        acc[i][j] = MFMA_BF16(wf[i], af[j], acc[i][j]);  // rows = n
  }

  // rows = n: acc[i][j][r] = C[m = w*32+j*16+lm][n = i*16+quad*4+r]
#pragma unroll
  for (int i = 0; i < 4; ++i) {
    const int nb = n0 + i * 16 + quad * 4;
    const float4 bv4 = *(const float4*)(bias + nb);
#pragma unroll
    for (int j = 0; j < 2; ++j) {
      const int mg = m0 + w * 32 + j * 16 + lm;
      float4 o;
      o.x = acc[i][j][0] + bv4.x; o.y = acc[i][j][1] + bv4.y;
      o.z = acc[i][j][2] + bv4.z; o.w = acc[i][j][3] + bv4.w;
      *(float4*)(out + (size_t)mg * 1024 + nb) = o;
    }
  }
}

// ---------------------------------------------------------------------------
// Flash attention: DOUBLE-BUFFERED K/V staging, ONE barrier per kt-iter.
// Structure: stage(0); loop { sync; prefetch(kt+1); compute(kt); }.
// The __syncthreads-forced vmcnt(0) drain at iter kt+1 waits on a DMA that
// was issued a full compute phase earlier -> latency hidden (this is the
// restructuring the m97 2-barrier loop can't express; R4-R7 all stalled on
// the per-iter drain). 4 waves x 32 queries (LDS-traffic-optimal), Br=128,
// Bc=64, full t-range. No-max softmax (scores bounded ~|13|), Q pre-scaled,
// Q fragments direct from global (one-time). Ps PST=76: 0 conflicts (R5).
// ---------------------------------------------------------------------------
#define PST 76

__global__ __launch_bounds__(256) void flash_attn(
    const bf16* __restrict__ Q, const bf16* __restrict__ K,
    const bf16* __restrict__ Vt, bf16* __restrict__ O)
{
  __shared__ __align__(16) bf16 Kt[2][64 * 64];
  __shared__ __align__(16) bf16 Vs[2][64 * 64];
  __shared__ __align__(16) bf16 Ps[128 * PST];

  const int tid = threadIdx.x;
  const int w = tid >> 6, lane = tid & 63;
  const int lm = lane & 15, quad = lane >> 4;
  const int bh = blockIdx.y;
  const int s0 = blockIdx.x * 128;
  const size_t qkbase = (size_t)bh * (2048 * 64);
  const size_t vbase = (size_t)bh * (64 * 2048);

  // Q fragments direct from global (one-time; 16 rows x 64B per instr)
  bf16x8 qa[2][2];
#pragma unroll
  for (int g = 0; g < 2; ++g) {
    const bf16* qp = Q + qkbase + (size_t)(s0 + w * 32 + g * 16 + lm) * 64;
    qa[g][0] = *(const bf16x8*)(qp + quad * 8);
    qa[g][1] = *(const bf16x8*)(qp + 32 + quad * 8);
  }

  // staging indices (256 threads cover a 64x64 tile in 2 chunks)
  const int srow = tid >> 3, scs = tid & 7;
  const int scc = scs ^ (srow & 7);
  const int srow2 = (tid + 256) >> 3, scs2 = tid & 7;  // rows 32..63
  const int scc2 = scs2 ^ (srow2 & 7);

  // prefetch tile 0 into buffer 0
  {
    const int t0 = 0;
    gl_lds16(K + qkbase + (size_t)(t0 + srow) * 64 + scc * 8, Kt[0] + tid * 8);
    gl_lds16(Vt + vbase + (size_t)srow * 2048 + t0 + scc * 8, Vs[0] + tid * 8);
    gl_lds16(K + qkbase + (size_t)(t0 + srow2) * 64 + scc2 * 8,
             Kt[0] + (tid + 256) * 8);
    gl_lds16(Vt + vbase + (size_t)srow2 * 2048 + t0 + scc2 * 8,
             Vs[0] + (tid + 256) * 8);
  }

  f32x4 zero4 = {0.f, 0.f, 0.f, 0.f};
  float l_part[2] = {0.f, 0.f};
  f32x4 oacc[2][4];
#pragma unroll
  for (int g = 0; g < 2; ++g)
#pragma unroll
    for (int dt = 0; dt < 4; ++dt) oacc[g][dt] = zero4;

  const int prow[2] = {(w * 32 + lm) * PST, (w * 32 + 16 + lm) * PST};

  for (int kt = 0; kt < 32; ++kt) {
    const int cur = kt & 1;
    __syncthreads();  // drains my prefetch of tile kt; syncs readers of buf

    if (kt + 1 < 32) {  // prefetch tile kt+1 into the other buffer (async)
      const int t1 = (kt + 1) * 64, nb = cur ^ 1;
      gl_lds16(K + qkbase + (size_t)(t1 + srow) * 64 + scc * 8, Kt[nb] + tid * 8);
      gl_lds16(Vt + vbase + (size_t)srow * 2048 + t1 + scc * 8, Vs[nb] + tid * 8);
      gl_lds16(K + qkbase + (size_t)(t1 + srow2) * 64 + scc2 * 8,
               Kt[nb] + (tid + 256) * 8);
      gl_lds16(Vt + vbase + (size_t)srow2 * 2048 + t1 + scc2 * 8,
               Vs[nb] + (tid + 256) * 8);
    }

    // St = K.Q^T per group; p = exp2(st); pack P rows (wave-private)
#pragma unroll
    for (int c = 0; c < 4; ++c) {
      int row = c * 16 + lm;
      bf16x8 kb0 = *(const bf16x8*)(Kt[cur] + row * 64 + ((quad ^ (row & 7)) * 8));
      bf16x8 kb1 = *(const bf16x8*)(Kt[cur] + row * 64 + (((quad + 4) ^ (row & 7)) * 8));
#pragma unroll
      for (int g = 0; g < 2; ++g) {
        f32x4 z = MFMA_BF16(kb0, qa[g][0], zero4);
        f32x4 st = MFMA_BF16(kb1, qa[g][1], z);
        bf16x4 pk;
#pragma unroll
        for (int r = 0; r < 4; ++r) {
          float p = EXP2F(st[r]);
          l_part[g] += p;
          pk[r] = (bf16)p;
        }
        *(bf16x4*)(Ps + prow[g] + c * 16 + quad * 4) = pk;
      }
    }

    // O^T += V^T . P^T (in-wave lgkm ordering covers Ps write->read)
    bf16x8 pa[2][2];
#pragma unroll
    for (int g = 0; g < 2; ++g) {
      pa[g][0] = *(const bf16x8*)(Ps + prow[g] + quad * 8);
      pa[g][1] = *(const bf16x8*)(Ps + prow[g] + 32 + quad * 8);
    }
#pragma unroll
    for (int dt = 0; dt < 4; ++dt) {
      int row = dt * 16 + lm;
      bf16x8 va0 = *(const bf16x8*)(Vs[cur] + row * 64 + ((quad ^ (row & 7)) * 8));
      bf16x8 va1 = *(const bf16x8*)(Vs[cur] + row * 64 + (((quad + 4) ^ (row & 7)) * 8));
#pragma unroll
      for (int g = 0; g < 2; ++g) {
        oacc[g][dt] = MFMA_BF16(va0, pa[g][0], oacc[g][dt]);
        oacc[g][dt] = MFMA_BF16(va1, pa[g][1], oacc[g][dt]);
      }
    }
  }

  // final denom (2 shuffles/group), normalize, bounce O^T rows through Ps
  const int b = bh >> 4, hh = bh & 15;
#pragma unroll
  for (int g = 0; g < 2; ++g) {
    float l = l_part[g];
    l += __shfl_xor(l, 16, 64);
    l += __shfl_xor(l, 32, 64);
    float inv = 1.f / l;
#pragma unroll
    for (int dt = 0; dt < 4; ++dt)
#pragma unroll
      for (int r = 0; r < 4; ++r)
        Ps[prow[g] + dt * 16 + quad * 4 + r] = (bf16)(oacc[g][dt][r] * inv);

    const int sq = s0 + w * 32 + g * 16 + lm;
    const size_t ob = ((size_t)(b * 2048 + sq)) * 1024 + hh * 64;
#pragma unroll
    for (int half = 0; half < 2; ++half) {
      bf16x8 ov = *(const bf16x8*)(Ps + prow[g] + (half * 4 + quad) * 8);
      *(bf16x8*)(O + ob + (half * 4 + quad) * 8) = ov;
    }
  }
}

// ---------------------------------------------------------------------------
extern "C" void kernel_launch(void* const* d_in, const int* in_sizes, int n_in,
                              void* d_out, int out_size, void* d_ws, size_t ws_size,
                              hipStream_t stream) {
  (void)in_sizes; (void)n_in; (void)out_size; (void)ws_size;
  const float* q   = (const float*)d_in[0];
  const float* k   = (const float*)d_in[1];
  const float* v   = (const float*)d_in[2];
  const float* kpe = (const float*)d_in[3];
  const float* Wq  = (const float*)d_in[4];
  const float* bq  = (const float*)d_in[5];
  const float* Wk  = (const float*)d_in[6];
  const float* bk  = (const float*)d_in[7];
  const float* Wv  = (const float*)d_in[8];
  const float* bv  = (const float*)d_in[9];
  const float* Wo  = (const float*)d_in[10];
  const float* bo  = (const float*)d_in[11];

  const size_t NT = 4u * 1024 * 1024;  // 4M elems per [4096,1024] tensor
  bf16* ws  = (bf16*)d_ws;
  bf16* Wt  = ws;            // 4 x 1M elems (bf16 W^T for Wq,Wk,Wv,Wo)
  bf16* qb  = Wt + NT;       // bf16 copies of q,k,v
  bf16* kb  = qb + NT;
  bf16* vb  = kb + NT;
  bf16* Qs  = vb + NT;       // [bh][s][d], pre-scaled
  bf16* Ks  = Qs + NT;       // K_eff [bh][t][d] (kpe folded in epilogue)
  bf16* Vts = Ks + NT;       // V^T  [bh][d][t] (direct from GEMM)
  bf16* Oa  = Vts + NT;      // attn out [b][s][h*64+d]

  prep<<<dim3(7168), 256, 0, stream>>>(q, k, v, qb, kb, vb, Wq, Wk, Wv, Wo, Wt);
  qkv_gemm<<<dim3(8, 32, 3), 256, 0, stream>>>(qb, kb, vb, Wt, bq, bk, bv, kpe,
                                               Qs, Ks, Vts);
  flash_attn<<<dim3(16, 32), 256, 0, stream>>>(Qs, Ks, Vts, Oa);
  out_gemm<<<dim3(16, 32), 256, 0, stream>>>(Oa, Wt + 3u * 1024 * 1024, bo,
                                             (float*)d_out);
}